// Round 1
// baseline (1776.293 us; speedup 1.0000x reference)
//
#include <hip/hip_runtime.h>

#define TT 4096
#define NB 512
#define NH 10
#define HP 16
#define NL 8
#define BPG 4   // batch elements per workgroup (one 16-lane group each)

// One workgroup = 8 waves (one per layer), 4 batch elements.
// Wave l at step s computes timestep t = s - l (diagonal wavefront).
// Inter-layer + own-recurrence state flows through a depth-2 LDS ring.
__global__ __launch_bounds__(512, 1)
void rnn_pipe(const float* __restrict__ x, const float* __restrict__ h0,
              const float* __restrict__ w_ih0, const float* __restrict__ w_ih_rest,
              const float* __restrict__ w_hh, const float* __restrict__ b_ih,
              const float* __restrict__ b_hh, const float* __restrict__ w_lin,
              const float* __restrict__ b_lin, float* __restrict__ out)
{
    __shared__ float ring[NL][2][BPG][HP];

    const int tid  = threadIdx.x;
    const int wv   = tid >> 6;          // layer index = wave index
    const int lane = tid & 63;
    const int g    = lane >> 4;         // batch group within wave
    const int h    = lane & 15;         // hidden unit (padded 10->16)
    const int b    = blockIdx.x * BPG + g;

    // ---- per-lane weights (loaded once) ----
    float wih[NH], whh[NH];
    float bias = 0.f, w0 = 0.f, wl = 0.f;
    #pragma unroll
    for (int j = 0; j < NH; ++j) { wih[j] = 0.f; whh[j] = 0.f; }
    if (h < NH) {
        bias = b_ih[wv*NH + h] + b_hh[wv*NH + h];
        if (wv == 0) {
            w0 = w_ih0[h];                       // [H,1]
        } else {
            #pragma unroll
            for (int j = 0; j < NH; ++j)
                wih[j] = w_ih_rest[((wv-1)*NH + h)*NH + j];
        }
        #pragma unroll
        for (int j = 0; j < NH; ++j)
            whh[j] = w_hh[(wv*NH + h)*NH + j];
        if (wv == NL-1) wl = w_lin[h];
    }
    const float blin = b_lin[0];

    // initial state into the t = -1 slot (slot 1)
    ring[wv][1][g][h] = (h < NH) ? h0[(wv*NB + b)*NH + h] : 0.f;

    // layer-0 x prefetch: lane h holds x[b][blk*16 + h]
    float xcur = 0.f, xnext = 0.f;
    if (wv == 0) xnext = x[b*TT + h];   // block 0 (t = 0..15)
    float yst = 0.f;

    __syncthreads();

    for (int s = 0; s < TT + NL - 1; ++s) {
        const int t = s - wv;
        if (t >= 0 && t < TT) {                    // wave-uniform branch
            const int rs = t & 1, ps = rs ^ 1;
            float a0, a1 = 0.f;
            if (wv == 0) {
                if ((t & 15) == 0) {               // rotate prefetch buffers
                    xcur = xnext;
                    const int pt = t + 16 + h;     // prefetch next block (used 16 steps later)
                    xnext = (pt < TT) ? x[b*TT + pt] : 0.f;
                }
                const float xs = __shfl(xcur, (lane & 48) | (t & 15));
                a0 = fmaf(w0, xs, bias);
            } else {
                const float* ip = &ring[wv-1][rs][g][0];
                const float4 i0 = *(const float4*)(ip);
                const float4 i1 = *(const float4*)(ip + 4);
                const float2 i2 = *(const float2*)(ip + 8);
                a0 = bias;
                a0 = fmaf(wih[0], i0.x, a0); a1 = fmaf(wih[1], i0.y, a1);
                a0 = fmaf(wih[2], i0.z, a0); a1 = fmaf(wih[3], i0.w, a1);
                a0 = fmaf(wih[4], i1.x, a0); a1 = fmaf(wih[5], i1.y, a1);
                a0 = fmaf(wih[6], i1.z, a0); a1 = fmaf(wih[7], i1.w, a1);
                a0 = fmaf(wih[8], i2.x, a0); a1 = fmaf(wih[9], i2.y, a1);
            }
            // recurrence dot: own previous h vector from the other ring slot
            const float* hp = &ring[wv][ps][g][0];
            const float4 p0 = *(const float4*)(hp);
            const float4 p1 = *(const float4*)(hp + 4);
            const float2 p2 = *(const float2*)(hp + 8);
            float r0 = 0.f, r1 = 0.f;
            r0 = fmaf(whh[0], p0.x, r0); r1 = fmaf(whh[1], p0.y, r1);
            r0 = fmaf(whh[2], p0.z, r0); r1 = fmaf(whh[3], p0.w, r1);
            r0 = fmaf(whh[4], p1.x, r0); r1 = fmaf(whh[5], p1.y, r1);
            r0 = fmaf(whh[6], p1.z, r0); r1 = fmaf(whh[7], p1.w, r1);
            r0 = fmaf(whh[8], p2.x, r0); r1 = fmaf(whh[9], p2.y, r1);

            const float z  = (a0 + a1) + (r0 + r1);
            const float u  = __expf(2.f * z);                       // v_exp_f32
            const float th = 1.f - 2.f * __builtin_amdgcn_rcpf(u + 1.f); // tanh(z)

            ring[wv][rs][g][h] = th;

            if (wv == NL-1) {
                // fused final linear: y[b][t] = sum_h wl[h]*th[h] + b_lin
                float py = wl * th;
                py += __shfl_xor(py, 1, 16);
                py += __shfl_xor(py, 2, 16);
                py += __shfl_xor(py, 4, 16);
                py += __shfl_xor(py, 8, 16);
                py += blin;
                if (h == (t & 15)) yst = py;       // stage own t-slot
                if ((t & 15) == 15)                // coalesced store every 16 steps
                    out[b*TT + (t & ~15) + h] = yst;
            }
            if (t == TT-1 && h < NH)               // final hidden states h1[L,B,H]
                out[NB*TT + (wv*NB + b)*NH + h] = th;
        }
        __syncthreads();
    }
}

extern "C" void kernel_launch(void* const* d_in, const int* in_sizes, int n_in,
                              void* d_out, int out_size, void* d_ws, size_t ws_size,
                              hipStream_t stream) {
    const float* x         = (const float*)d_in[0];
    const float* h0        = (const float*)d_in[1];
    const float* w_ih0     = (const float*)d_in[2];
    const float* w_ih_rest = (const float*)d_in[3];
    const float* w_hh      = (const float*)d_in[4];
    const float* b_ih      = (const float*)d_in[5];
    const float* b_hh      = (const float*)d_in[6];
    const float* w_lin     = (const float*)d_in[7];
    const float* b_lin     = (const float*)d_in[8];
    float* out = (float*)d_out;

    rnn_pipe<<<dim3(NB / BPG), dim3(512), 0, stream>>>(
        x, h0, w_ih0, w_ih_rest, w_hh, b_ih, b_hh, w_lin, b_lin, out);
}